// Round 1
// 1120.009 us; speedup vs baseline: 1.2834x; 1.2834x over previous
//
#include <hip/hip_runtime.h>
#include <hip/hip_bf16.h>

typedef __hip_bfloat16 bf16;

#define F_DIM 64
#define ATOMS_PER_BLOCK 32
#define ATOMS_PER_WAVE 8

__device__ __forceinline__ float b2f(bf16 v) { return __bfloat162float(v); }
__device__ __forceinline__ bf16  f2b(float v) { return __float2bfloat16(v); }

// Load element i of a float tensor whose storage dtype is fp32 (F32=true) or bf16.
template <bool F32>
__device__ __forceinline__ float ldf(const void* p, size_t i) {
    if (F32) return ((const float*)p)[i];
    return b2f(((const bf16*)p)[i]);
}

// Non-temporal variant (streaming reads that should not evict L2-resident tables).
template <bool F32>
__device__ __forceinline__ float ldnt(const void* p, size_t i) {
    if (F32) return __builtin_nontemporal_load((const float*)p + i);
    unsigned short u = __builtin_nontemporal_load((const unsigned short*)p + i);
    unsigned v = ((unsigned)u) << 16;
    float f; __builtin_memcpy(&f, &v, 4);
    return f;
}

// ---------------------------------------------------------------------------
// Kernel 0: dtype detection.
//  flags[0] = 1 if float tensors are stored fp32, 0 if bf16
//  flags[1] = 1 if index tensors are stored int64, 0 if int32
// ---------------------------------------------------------------------------
__global__ void detect_kernel(const void* emb, const void* idxi, int* flags)
{
    if (threadIdx.x == 0 && blockIdx.x == 0) {
        const unsigned short* u = (const unsigned short*)emb;
        int sane = 0;
        for (int k = 0; k < 128; k++) {
            unsigned short b = u[2 * k];
            unsigned e = (b >> 7) & 0xFF;
            if ((b & 0x7FFF) == 0 || (e >= 117 && e <= 137)) sane++;
        }
        const unsigned* w = (const unsigned*)idxi;
        int zhi = 0;
        for (int k = 0; k < 128; k++)
            if (w[2 * k + 1] == 0u) zhi++;
        flags[0] = (sane < 64) ? 1 : 0;   // not sane as bf16 -> fp32 storage
        flags[1] = (zhi >= 64) ? 1 : 0;   // high words all zero -> int64
    }
}

// ---------------------------------------------------------------------------
// Kernel 1: per-atom MLP  x = (silu(emb@W1 + b1)) @ W2 + b2   -> ws (fp32)
// (unchanged from previous version)
// ---------------------------------------------------------------------------
template <bool F32>
__global__ __launch_bounds__(256) void atom_transform_kernel(
    const int* __restrict__ flags,
    const void* __restrict__ emb, const void* __restrict__ W1,
    const void* __restrict__ b1, const void* __restrict__ W2,
    const void* __restrict__ b2, float* __restrict__ x, int n_atoms)
{
    if ((flags[0] != 0) != F32) return;

    __shared__ float semb[ATOMS_PER_BLOCK][F_DIM];  // 8 KB
    __shared__ float sh[ATOMS_PER_BLOCK][F_DIM];    // 8 KB

    int t = threadIdx.x;
    int atom0 = blockIdx.x * ATOMS_PER_BLOCK;
    for (int i = t; i < ATOMS_PER_BLOCK * F_DIM; i += 256) {
        int a = atom0 + (i >> 6);
        semb[i >> 6][i & 63] = (a < n_atoms) ? ldf<F32>(emb, (size_t)a * F_DIM + (i & 63)) : 0.f;
    }
    __syncthreads();

    int wave = t >> 6, lane = t & 63;
    int ab = wave * ATOMS_PER_WAVE;

    float acc1[ATOMS_PER_WAVE];
    #pragma unroll
    for (int a = 0; a < ATOMS_PER_WAVE; a++) acc1[a] = ldf<F32>(b1, lane);
    for (int f = 0; f < F_DIM; f++) {
        float w = ldf<F32>(W1, (size_t)f * 64 + lane);
        #pragma unroll
        for (int a = 0; a < ATOMS_PER_WAVE; a++) acc1[a] += semb[ab + a][f] * w;
    }
    #pragma unroll
    for (int a = 0; a < ATOMS_PER_WAVE; a++) {
        float v = acc1[a];
        sh[ab + a][lane] = v / (1.f + __expf(-v));   // silu
    }

    float a0[ATOMS_PER_WAVE], a1[ATOMS_PER_WAVE], a2[ATOMS_PER_WAVE];
    #pragma unroll
    for (int a = 0; a < ATOMS_PER_WAVE; a++) {
        a0[a] = ldf<F32>(b2, lane);
        a1[a] = ldf<F32>(b2, 64 + lane);
        a2[a] = ldf<F32>(b2, 128 + lane);
    }
    for (int g = 0; g < F_DIM; g++) {
        float w0 = ldf<F32>(W2, (size_t)g * 192 + lane);
        float w1 = ldf<F32>(W2, (size_t)g * 192 + 64 + lane);
        float w2 = ldf<F32>(W2, (size_t)g * 192 + 128 + lane);
        #pragma unroll
        for (int a = 0; a < ATOMS_PER_WAVE; a++) {
            float hg = sh[ab + a][g];
            a0[a] += hg * w0; a1[a] += hg * w1; a2[a] += hg * w2;
        }
    }
    #pragma unroll
    for (int a = 0; a < ATOMS_PER_WAVE; a++) {
        int atom = atom0 + ab + a;
        if (atom < n_atoms) {
            size_t base = (size_t)atom * 192;
            x[base + lane]       = a0[a];
            x[base + 64 + lane]  = a1[a];
            x[base + 128 + lane] = a2[a];
        }
    }
}

// ---------------------------------------------------------------------------
// Kernel 2: zero the histogram (ws is poisoned 0xAA before each call)
// ---------------------------------------------------------------------------
__global__ void zero_hist_kernel(int* __restrict__ hist, int n)
{
    int stride = gridDim.x * blockDim.x;
    for (int k = blockIdx.x * blockDim.x + threadIdx.x; k < n; k += stride)
        hist[k] = 0;
}

// ---------------------------------------------------------------------------
// Kernel 3: histogram of idx_i  (800K int atomics over 100KB -> L2-resident)
// ---------------------------------------------------------------------------
template <bool IDX64>
__global__ __launch_bounds__(256) void hist_kernel(
    const int* __restrict__ flags, const void* __restrict__ idx_i,
    int* __restrict__ hist, int n_pairs)
{
    if ((flags[1] != 0) != IDX64) return;
    int e = blockIdx.x * 256 + threadIdx.x;
    if (e < n_pairs) {
        int i = IDX64 ? (int)((const long long*)idx_i)[e] : ((const int*)idx_i)[e];
        atomicAdd(&hist[i], 1);
    }
}

// ---------------------------------------------------------------------------
// Kernel 4: exclusive prefix sum over hist -> start[0..n] and cursor copy.
// Single block of 1024 threads, 25 chunks of 1024 for n=25000.
// ---------------------------------------------------------------------------
__global__ __launch_bounds__(1024) void scan_kernel(
    const int* __restrict__ hist, int* __restrict__ start,
    int* __restrict__ cursor, int n)
{
    __shared__ int wsum[16];
    __shared__ int ctot;
    __shared__ int runsh;
    int t = threadIdx.x, lane = t & 63, wv = t >> 6;
    if (t == 0) runsh = 0;
    __syncthreads();

    for (int base = 0; base < n; base += 1024) {
        int idx = base + t;
        int v = (idx < n) ? hist[idx] : 0;
        int s = v;
        #pragma unroll
        for (int d = 1; d < 64; d <<= 1) {
            int u = __shfl_up(s, d, 64);
            if (lane >= d) s += u;
        }
        if (lane == 63) wsum[wv] = s;
        __syncthreads();
        if (wv == 0) {
            int w_ = (lane < 16) ? wsum[lane] : 0;
            #pragma unroll
            for (int d = 1; d < 16; d <<= 1) {
                int u = __shfl_up(w_, d, 64);
                if (lane >= d && lane < 16) w_ += u;
            }
            if (lane < 16) wsum[lane] = w_;
            if (lane == 15) ctot = w_;
        }
        __syncthreads();
        int woff = wv ? wsum[wv - 1] : 0;
        int excl = runsh + woff + s - v;
        if (idx < n) { start[idx] = excl; cursor[idx] = excl; }
        __syncthreads();                 // everyone has read runsh/wsum
        if (t == 0) runsh += ctot;
        __syncthreads();                 // runsh update visible; wsum reusable
    }
    if (t == 0) start[n] = runsh;
}

// ---------------------------------------------------------------------------
// Kernel 5: scatter pair ids into per-atom buckets (counting sort)
// ---------------------------------------------------------------------------
template <bool IDX64>
__global__ __launch_bounds__(256) void scatter_kernel(
    const int* __restrict__ flags, const void* __restrict__ idx_i,
    int* __restrict__ cursor, int* __restrict__ perm, int n_pairs)
{
    if ((flags[1] != 0) != IDX64) return;
    int e = blockIdx.x * 256 + threadIdx.x;
    if (e < n_pairs) {
        int i = IDX64 ? (int)((const long long*)idx_i)[e] : ((const int*)idx_i)[e];
        int pos = atomicAdd(&cursor[i], 1);
        perm[pos] = e;
    }
}

// ---------------------------------------------------------------------------
// Kernel 6: gather-reduce + finalize. One wave per atom, zero atomics.
// Lane = feature. Pair ids batched 64-at-a-time, broadcast via __shfl.
// Writes final out = base + aggregate directly (finalize fused).
// ---------------------------------------------------------------------------
template <bool F32, bool IDX64>
__global__ __launch_bounds__(256) void gather_kernel(
    const int* __restrict__ flags,
    const void* __restrict__ Wij, const void* __restrict__ dir_ij,
    const void* __restrict__ idx_j, const float* __restrict__ x,
    const void* __restrict__ mu, const void* __restrict__ emb,
    const int* __restrict__ start, const int* __restrict__ perm,
    void* __restrict__ out, int n_atoms)
{
    if ((flags[0] != 0) != F32) return;
    if ((flags[1] != 0) != IDX64) return;

    int lane = threadIdx.x & 63;
    int i = blockIdx.x * 4 + (threadIdx.x >> 6);
    if (i >= n_atoms) return;

    int s = start[i];
    int cnt = start[i + 1] - s;

    float dq = 0.f, dm0 = 0.f, dm1 = 0.f, dm2 = 0.f;

    for (int base = 0; base < cnt; base += 64) {
        int m = cnt - base; if (m > 64) m = 64;
        int e = 0, j = 0;
        float d0 = 0.f, d1 = 0.f, d2 = 0.f;
        if (lane < m) {
            e = perm[s + base + lane];
            j = IDX64 ? (int)((const long long*)idx_j)[e] : ((const int*)idx_j)[e];
            d0 = ldf<F32>(dir_ij, (size_t)e * 3 + 0);
            d1 = ldf<F32>(dir_ij, (size_t)e * 3 + 1);
            d2 = ldf<F32>(dir_ij, (size_t)e * 3 + 2);
        }
        #pragma unroll 2
        for (int p = 0; p < m; p++) {
            int e2 = __shfl(e, p, 64);
            int j2 = __shfl(j, p, 64);
            float D0 = __shfl(d0, p, 64);
            float D1 = __shfl(d1, p, 64);
            float D2 = __shfl(d2, p, 64);
            size_t wb = (size_t)e2 * 192;
            size_t xb = (size_t)j2 * 192;
            // Wij is a 614MB one-shot stream: non-temporal so it doesn't
            // evict the L2/L3-resident x/mu/idx_j/dir tables.
            float w0 = ldnt<F32>(Wij, wb + lane);
            float w1 = ldnt<F32>(Wij, wb + 64 + lane);
            float w2 = ldnt<F32>(Wij, wb + 128 + lane);
            float x0 = x[xb + lane];
            float x1 = x[xb + 64 + lane];
            float x2 = x[xb + 128 + lane];
            float m0 = ldf<F32>(mu, xb + lane);
            float m1 = ldf<F32>(mu, xb + 64 + lane);
            float m2 = ldf<F32>(mu, xb + 128 + lane);
            float dmuR  = w1 * x1;
            float dmumu = w2 * x2;
            dq  += w0 * x0;
            dm0 += dmuR * D0 + dmumu * m0;
            dm1 += dmuR * D1 + dmumu * m1;
            dm2 += dmuR * D2 + dmumu * m2;
        }
    }

    size_t nq = (size_t)n_atoms * 64;
    float qv = ldf<F32>(emb, (size_t)i * 64 + lane) + dq;
    size_t mb = (size_t)i * 192;
    float o0 = ldf<F32>(mu, mb + lane) + dm0;
    float o1 = ldf<F32>(mu, mb + 64 + lane) + dm1;
    float o2 = ldf<F32>(mu, mb + 128 + lane) + dm2;
    if (F32) {
        float* o = (float*)out;
        o[(size_t)i * 64 + lane]   = qv;
        o[nq + mb + lane]          = o0;
        o[nq + mb + 64 + lane]     = o1;
        o[nq + mb + 128 + lane]    = o2;
    } else {
        bf16* o = (bf16*)out;
        o[(size_t)i * 64 + lane]   = f2b(qv);
        o[nq + mb + lane]          = f2b(o0);
        o[nq + mb + 64 + lane]     = f2b(o1);
        o[nq + mb + 128 + lane]    = f2b(o2);
    }
}

// ---------------------------------------------------------------------------
extern "C" void kernel_launch(void* const* d_in, const int* in_sizes, int n_in,
                              void* d_out, int out_size, void* d_ws, size_t ws_size,
                              hipStream_t stream)
{
    const void* emb   = d_in[0];
    const void* mu    = d_in[1];
    const void* Wij   = d_in[2];
    const void* dirij = d_in[3];
    const void* idx_i = d_in[4];
    const void* idx_j = d_in[5];
    const void* W1    = d_in[6];
    const void* b1    = d_in[7];
    const void* W2    = d_in[8];
    const void* b2    = d_in[9];

    int n_atoms = in_sizes[0] / 64;     // (N,1,64)
    int n_pairs = in_sizes[2] / 192;    // (E,1,192)

    // Workspace layout:
    //   flags  : 2 ints, 256B slot
    //   x      : n_atoms*192 f32   (atom MLP output)
    //   hist   : n_atoms   int
    //   start  : n_atoms+1 int     (exclusive prefix sum)
    //   cursor : n_atoms   int     (scatter cursors)
    //   perm   : n_pairs   int     (pair ids sorted by idx_i)
    char* ws = (char*)d_ws;
    int*   flags  = (int*)ws;
    float* x      = (float*)(ws + 256);
    int*   hist   = (int*)(x + (size_t)n_atoms * 192);
    int*   start  = hist + n_atoms;
    int*   cursor = start + n_atoms + 1;
    int*   perm   = cursor + n_atoms;

    detect_kernel<<<1, 64, 0, stream>>>(emb, idx_i, flags);

    atom_transform_kernel<true ><<<(n_atoms + 31) / 32, 256, 0, stream>>>(flags, emb, W1, b1, W2, b2, x, n_atoms);
    atom_transform_kernel<false><<<(n_atoms + 31) / 32, 256, 0, stream>>>(flags, emb, W1, b1, W2, b2, x, n_atoms);

    zero_hist_kernel<<<128, 256, 0, stream>>>(hist, n_atoms);

    int pg = (n_pairs + 255) / 256;
    hist_kernel<false><<<pg, 256, 0, stream>>>(flags, idx_i, hist, n_pairs);
    hist_kernel<true ><<<pg, 256, 0, stream>>>(flags, idx_i, hist, n_pairs);

    scan_kernel<<<1, 1024, 0, stream>>>(hist, start, cursor, n_atoms);

    scatter_kernel<false><<<pg, 256, 0, stream>>>(flags, idx_i, cursor, perm, n_pairs);
    scatter_kernel<true ><<<pg, 256, 0, stream>>>(flags, idx_i, cursor, perm, n_pairs);

    int gg = (n_atoms + 3) / 4;   // 4 waves/block, 1 atom/wave
    gather_kernel<true , false><<<gg, 256, 0, stream>>>(flags, Wij, dirij, idx_j, x, mu, emb, start, perm, d_out, n_atoms);
    gather_kernel<true , true ><<<gg, 256, 0, stream>>>(flags, Wij, dirij, idx_j, x, mu, emb, start, perm, d_out, n_atoms);
    gather_kernel<false, false><<<gg, 256, 0, stream>>>(flags, Wij, dirij, idx_j, x, mu, emb, start, perm, d_out, n_atoms);
    gather_kernel<false, true ><<<gg, 256, 0, stream>>>(flags, Wij, dirij, idx_j, x, mu, emb, start, perm, d_out, n_atoms);
}

// Round 2
// 1095.265 us; speedup vs baseline: 1.3124x; 1.0226x over previous
//
#include <hip/hip_runtime.h>
#include <hip/hip_bf16.h>

typedef __hip_bfloat16 bf16;

#define F_DIM 64
#define ATOMS_PER_BLOCK 32
#define ATOMS_PER_WAVE 8

__device__ __forceinline__ float b2f(bf16 v) { return __bfloat162float(v); }
__device__ __forceinline__ bf16  f2b(float v) { return __float2bfloat16(v); }

// Load element i of a float tensor whose storage dtype is fp32 (F32=true) or bf16.
template <bool F32>
__device__ __forceinline__ float ldf(const void* p, size_t i) {
    if (F32) return ((const float*)p)[i];
    return b2f(((const bf16*)p)[i]);
}

// Non-temporal variant (streaming reads that should not evict L2-resident tables).
template <bool F32>
__device__ __forceinline__ float ldnt(const void* p, size_t i) {
    if (F32) return __builtin_nontemporal_load((const float*)p + i);
    unsigned short u = __builtin_nontemporal_load((const unsigned short*)p + i);
    unsigned v = ((unsigned)u) << 16;
    float f; __builtin_memcpy(&f, &v, 4);
    return f;
}

__device__ __forceinline__ int ldidx(const void* p, int e, bool idx64) {
    return idx64 ? (int)((const long long*)p)[e] : ((const int*)p)[e];
}

// ---------------------------------------------------------------------------
// Kernel 0: dtype detection (wave-parallel) + histogram zeroing fused.
//  flags[0] = 1 if float tensors are stored fp32, 0 if bf16
//  flags[1] = 1 if index tensors are stored int64, 0 if int32
// Block 0 / wave 0 does detection with 64 parallel lanes (the old single-
// thread version was ~256 serial HBM-latency loads = up to ~100us).
// All blocks grid-stride zero the histogram.
// ---------------------------------------------------------------------------
__global__ __launch_bounds__(256) void detect_zero_kernel(
    const void* __restrict__ emb, const void* __restrict__ idxi,
    int* __restrict__ flags, int* __restrict__ hist, int n_atoms)
{
    int stride = gridDim.x * blockDim.x;
    for (int k = blockIdx.x * blockDim.x + threadIdx.x; k < n_atoms; k += stride)
        hist[k] = 0;

    if (blockIdx.x == 0 && threadIdx.x < 64) {
        int lane = threadIdx.x;
        const unsigned short* u = (const unsigned short*)emb;
        int sane = 0;
        #pragma unroll
        for (int k = lane; k < 128; k += 64) {
            unsigned short b = u[2 * k];
            unsigned e = (b >> 7) & 0xFF;
            if ((b & 0x7FFF) == 0 || (e >= 117 && e <= 137)) sane++;
        }
        const unsigned* w = (const unsigned*)idxi;
        int zhi = 0;
        #pragma unroll
        for (int k = lane; k < 128; k += 64)
            if (w[2 * k + 1] == 0u) zhi++;
        #pragma unroll
        for (int d = 1; d < 64; d <<= 1) {
            sane += __shfl_xor(sane, d, 64);
            zhi  += __shfl_xor(zhi,  d, 64);
        }
        if (lane == 0) {
            flags[0] = (sane < 64) ? 1 : 0;   // not sane as bf16 -> fp32 storage
            flags[1] = (zhi >= 64) ? 1 : 0;   // high words all zero -> int64
        }
    }
}

// ---------------------------------------------------------------------------
// Kernel 1: per-atom MLP  x = (silu(emb@W1 + b1)) @ W2 + b2   -> ws (fp32)
// Single launch; runtime wave-uniform branch on storage dtype.
// ---------------------------------------------------------------------------
template <bool F32>
__device__ __forceinline__ void atom_transform_body(
    const void* __restrict__ emb, const void* __restrict__ W1,
    const void* __restrict__ b1, const void* __restrict__ W2,
    const void* __restrict__ b2, float* __restrict__ x, int n_atoms,
    float (*semb)[F_DIM], float (*sh)[F_DIM])
{
    int t = threadIdx.x;
    int atom0 = blockIdx.x * ATOMS_PER_BLOCK;
    for (int i = t; i < ATOMS_PER_BLOCK * F_DIM; i += 256) {
        int a = atom0 + (i >> 6);
        semb[i >> 6][i & 63] = (a < n_atoms) ? ldf<F32>(emb, (size_t)a * F_DIM + (i & 63)) : 0.f;
    }
    __syncthreads();

    int wave = t >> 6, lane = t & 63;
    int ab = wave * ATOMS_PER_WAVE;

    float acc1[ATOMS_PER_WAVE];
    #pragma unroll
    for (int a = 0; a < ATOMS_PER_WAVE; a++) acc1[a] = ldf<F32>(b1, lane);
    for (int f = 0; f < F_DIM; f++) {
        float w = ldf<F32>(W1, (size_t)f * 64 + lane);
        #pragma unroll
        for (int a = 0; a < ATOMS_PER_WAVE; a++) acc1[a] += semb[ab + a][f] * w;
    }
    #pragma unroll
    for (int a = 0; a < ATOMS_PER_WAVE; a++) {
        float v = acc1[a];
        sh[ab + a][lane] = v / (1.f + __expf(-v));   // silu
    }
    // each wave only reads its own rows of sh -> no barrier needed

    float a0[ATOMS_PER_WAVE], a1[ATOMS_PER_WAVE], a2[ATOMS_PER_WAVE];
    #pragma unroll
    for (int a = 0; a < ATOMS_PER_WAVE; a++) {
        a0[a] = ldf<F32>(b2, lane);
        a1[a] = ldf<F32>(b2, 64 + lane);
        a2[a] = ldf<F32>(b2, 128 + lane);
    }
    for (int g = 0; g < F_DIM; g++) {
        float w0 = ldf<F32>(W2, (size_t)g * 192 + lane);
        float w1 = ldf<F32>(W2, (size_t)g * 192 + 64 + lane);
        float w2 = ldf<F32>(W2, (size_t)g * 192 + 128 + lane);
        #pragma unroll
        for (int a = 0; a < ATOMS_PER_WAVE; a++) {
            float hg = sh[ab + a][g];
            a0[a] += hg * w0; a1[a] += hg * w1; a2[a] += hg * w2;
        }
    }
    #pragma unroll
    for (int a = 0; a < ATOMS_PER_WAVE; a++) {
        int atom = atom0 + ab + a;
        if (atom < n_atoms) {
            size_t base = (size_t)atom * 192;
            x[base + lane]       = a0[a];
            x[base + 64 + lane]  = a1[a];
            x[base + 128 + lane] = a2[a];
        }
    }
}

__global__ __launch_bounds__(256) void atom_transform_kernel(
    const int* __restrict__ flags,
    const void* __restrict__ emb, const void* __restrict__ W1,
    const void* __restrict__ b1, const void* __restrict__ W2,
    const void* __restrict__ b2, float* __restrict__ x, int n_atoms)
{
    __shared__ float semb[ATOMS_PER_BLOCK][F_DIM];  // 8 KB
    __shared__ float sh[ATOMS_PER_BLOCK][F_DIM];    // 8 KB
    if (flags[0] != 0)
        atom_transform_body<true >(emb, W1, b1, W2, b2, x, n_atoms, semb, sh);
    else
        atom_transform_body<false>(emb, W1, b1, W2, b2, x, n_atoms, semb, sh);
}

// ---------------------------------------------------------------------------
// Kernel 2: histogram of idx_i  (800K int atomics over 100KB -> L2-resident)
// ---------------------------------------------------------------------------
__global__ __launch_bounds__(256) void hist_kernel(
    const int* __restrict__ flags, const void* __restrict__ idx_i,
    int* __restrict__ hist, int n_pairs)
{
    bool idx64 = flags[1] != 0;
    int e = blockIdx.x * 256 + threadIdx.x;
    if (e < n_pairs)
        atomicAdd(&hist[ldidx(idx_i, e, idx64)], 1);
}

// ---------------------------------------------------------------------------
// Kernel 3: exclusive prefix sum over hist -> start[0..n] and cursor copy.
// Single block of 1024 threads, 25 chunks of 1024 for n=25000.
// ---------------------------------------------------------------------------
__global__ __launch_bounds__(1024) void scan_kernel(
    const int* __restrict__ hist, int* __restrict__ start,
    int* __restrict__ cursor, int n)
{
    __shared__ int wsum[16];
    __shared__ int ctot;
    __shared__ int runsh;
    int t = threadIdx.x, lane = t & 63, wv = t >> 6;
    if (t == 0) runsh = 0;
    __syncthreads();

    for (int base = 0; base < n; base += 1024) {
        int idx = base + t;
        int v = (idx < n) ? hist[idx] : 0;
        int s = v;
        #pragma unroll
        for (int d = 1; d < 64; d <<= 1) {
            int u = __shfl_up(s, d, 64);
            if (lane >= d) s += u;
        }
        if (lane == 63) wsum[wv] = s;
        __syncthreads();
        if (wv == 0) {
            int w_ = (lane < 16) ? wsum[lane] : 0;
            #pragma unroll
            for (int d = 1; d < 16; d <<= 1) {
                int u = __shfl_up(w_, d, 64);
                if (lane >= d && lane < 16) w_ += u;
            }
            if (lane < 16) wsum[lane] = w_;
            if (lane == 15) ctot = w_;
        }
        __syncthreads();
        int woff = wv ? wsum[wv - 1] : 0;
        int excl = runsh + woff + s - v;
        if (idx < n) { start[idx] = excl; cursor[idx] = excl; }
        __syncthreads();                 // everyone has read runsh/wsum
        if (t == 0) runsh += ctot;
        __syncthreads();                 // runsh update visible; wsum reusable
    }
    if (t == 0) start[n] = runsh;
}

// ---------------------------------------------------------------------------
// Kernel 4: scatter pair ids into per-atom buckets (counting sort)
// ---------------------------------------------------------------------------
__global__ __launch_bounds__(256) void scatter_kernel(
    const int* __restrict__ flags, const void* __restrict__ idx_i,
    int* __restrict__ cursor, int* __restrict__ perm, int n_pairs)
{
    bool idx64 = flags[1] != 0;
    int e = blockIdx.x * 256 + threadIdx.x;
    if (e < n_pairs) {
        int pos = atomicAdd(&cursor[ldidx(idx_i, e, idx64)], 1);
        perm[pos] = e;
    }
}

// ---------------------------------------------------------------------------
// Kernel 5: gather-reduce + finalize. One wave per atom, zero atomics.
// Lane = feature. Pair ids batched 64-at-a-time, broadcast via __shfl.
// Writes final out = base + aggregate directly (finalize fused).
// ---------------------------------------------------------------------------
template <bool F32>
__device__ __forceinline__ void gather_body(
    const void* __restrict__ Wij, const void* __restrict__ dir_ij,
    const void* __restrict__ idx_j, const float* __restrict__ x,
    const void* __restrict__ mu, const void* __restrict__ emb,
    const int* __restrict__ start, const int* __restrict__ perm,
    void* __restrict__ out, int n_atoms, bool idx64)
{
    int lane = threadIdx.x & 63;
    int i = blockIdx.x * 4 + (threadIdx.x >> 6);
    if (i >= n_atoms) return;

    int s = start[i];
    int cnt = start[i + 1] - s;

    float dq = 0.f, dm0 = 0.f, dm1 = 0.f, dm2 = 0.f;

    for (int base = 0; base < cnt; base += 64) {
        int m = cnt - base; if (m > 64) m = 64;
        int e = 0, j = 0;
        float d0 = 0.f, d1 = 0.f, d2 = 0.f;
        if (lane < m) {
            e = perm[s + base + lane];
            j = ldidx(idx_j, e, idx64);
            d0 = ldf<F32>(dir_ij, (size_t)e * 3 + 0);
            d1 = ldf<F32>(dir_ij, (size_t)e * 3 + 1);
            d2 = ldf<F32>(dir_ij, (size_t)e * 3 + 2);
        }
        #pragma unroll 4
        for (int p = 0; p < m; p++) {
            int e2 = __shfl(e, p, 64);
            int j2 = __shfl(j, p, 64);
            float D0 = __shfl(d0, p, 64);
            float D1 = __shfl(d1, p, 64);
            float D2 = __shfl(d2, p, 64);
            size_t wb = (size_t)e2 * 192;
            size_t xb = (size_t)j2 * 192;
            // Wij is a 614MB one-shot stream: non-temporal so it doesn't
            // evict the L2/L3-resident x/mu/idx_j/dir tables.
            float w0 = ldnt<F32>(Wij, wb + lane);
            float w1 = ldnt<F32>(Wij, wb + 64 + lane);
            float w2 = ldnt<F32>(Wij, wb + 128 + lane);
            float x0 = x[xb + lane];
            float x1 = x[xb + 64 + lane];
            float x2 = x[xb + 128 + lane];
            float m0 = ldf<F32>(mu, xb + lane);
            float m1 = ldf<F32>(mu, xb + 64 + lane);
            float m2 = ldf<F32>(mu, xb + 128 + lane);
            float dmuR  = w1 * x1;
            float dmumu = w2 * x2;
            dq  += w0 * x0;
            dm0 += dmuR * D0 + dmumu * m0;
            dm1 += dmuR * D1 + dmumu * m1;
            dm2 += dmuR * D2 + dmumu * m2;
        }
    }

    size_t nq = (size_t)n_atoms * 64;
    float qv = ldf<F32>(emb, (size_t)i * 64 + lane) + dq;
    size_t mb = (size_t)i * 192;
    float o0 = ldf<F32>(mu, mb + lane) + dm0;
    float o1 = ldf<F32>(mu, mb + 64 + lane) + dm1;
    float o2 = ldf<F32>(mu, mb + 128 + lane) + dm2;
    if (F32) {
        float* o = (float*)out;
        o[(size_t)i * 64 + lane]   = qv;
        o[nq + mb + lane]          = o0;
        o[nq + mb + 64 + lane]     = o1;
        o[nq + mb + 128 + lane]    = o2;
    } else {
        bf16* o = (bf16*)out;
        o[(size_t)i * 64 + lane]   = f2b(qv);
        o[nq + mb + lane]          = f2b(o0);
        o[nq + mb + 64 + lane]     = f2b(o1);
        o[nq + mb + 128 + lane]    = f2b(o2);
    }
}

__global__ __launch_bounds__(256) void gather_kernel(
    const int* __restrict__ flags,
    const void* __restrict__ Wij, const void* __restrict__ dir_ij,
    const void* __restrict__ idx_j, const float* __restrict__ x,
    const void* __restrict__ mu, const void* __restrict__ emb,
    const int* __restrict__ start, const int* __restrict__ perm,
    void* __restrict__ out, int n_atoms)
{
    bool idx64 = flags[1] != 0;
    if (flags[0] != 0)
        gather_body<true >(Wij, dir_ij, idx_j, x, mu, emb, start, perm, out, n_atoms, idx64);
    else
        gather_body<false>(Wij, dir_ij, idx_j, x, mu, emb, start, perm, out, n_atoms, idx64);
}

// ---------------------------------------------------------------------------
extern "C" void kernel_launch(void* const* d_in, const int* in_sizes, int n_in,
                              void* d_out, int out_size, void* d_ws, size_t ws_size,
                              hipStream_t stream)
{
    const void* emb   = d_in[0];
    const void* mu    = d_in[1];
    const void* Wij   = d_in[2];
    const void* dirij = d_in[3];
    const void* idx_i = d_in[4];
    const void* idx_j = d_in[5];
    const void* W1    = d_in[6];
    const void* b1    = d_in[7];
    const void* W2    = d_in[8];
    const void* b2    = d_in[9];

    int n_atoms = in_sizes[0] / 64;     // (N,1,64)
    int n_pairs = in_sizes[2] / 192;    // (E,1,192)

    // Workspace layout:
    //   flags  : 2 ints, 256B slot
    //   x      : n_atoms*192 f32   (atom MLP output)
    //   hist   : n_atoms   int
    //   start  : n_atoms+1 int     (exclusive prefix sum)
    //   cursor : n_atoms   int     (scatter cursors)
    //   perm   : n_pairs   int     (pair ids sorted by idx_i)
    char* ws = (char*)d_ws;
    int*   flags  = (int*)ws;
    float* x      = (float*)(ws + 256);
    int*   hist   = (int*)(x + (size_t)n_atoms * 192);
    int*   start  = hist + n_atoms;
    int*   cursor = start + n_atoms + 1;
    int*   perm   = cursor + n_atoms;

    detect_zero_kernel<<<128, 256, 0, stream>>>(emb, idx_i, flags, hist, n_atoms);

    atom_transform_kernel<<<(n_atoms + 31) / 32, 256, 0, stream>>>(flags, emb, W1, b1, W2, b2, x, n_atoms);

    int pg = (n_pairs + 255) / 256;
    hist_kernel<<<pg, 256, 0, stream>>>(flags, idx_i, hist, n_pairs);

    scan_kernel<<<1, 1024, 0, stream>>>(hist, start, cursor, n_atoms);

    scatter_kernel<<<pg, 256, 0, stream>>>(flags, idx_i, cursor, perm, n_pairs);

    int gg = (n_atoms + 3) / 4;   // 4 waves/block, 1 atom/wave
    gather_kernel<<<gg, 256, 0, stream>>>(flags, Wij, dirij, idx_j, x, mu, emb, start, perm, d_out, n_atoms);
}